// Round 7
// baseline (329.743 us; speedup 1.0000x reference)
//
#include <hip/hip_runtime.h>
#include <hip/hip_bf16.h>

typedef __attribute__((ext_vector_type(8))) __bf16 bf16x8;
typedef __attribute__((ext_vector_type(4))) float f32x4;
typedef __attribute__((ext_vector_type(16))) float f32x16;
typedef __attribute__((ext_vector_type(4))) unsigned int u32x4;

#define DIM 1024
#define NHEADS 16
#define HDIM 64
#define BATCH 4
#define SEQ 2048
#define ROWS (BATCH * SEQ) /* 8192 */
#define SCL 0.18033688011112042f /* 0.125 * log2(e) */

__device__ inline unsigned short f2bf(float f) {
    __hip_bfloat16 h = __float2bfloat16(f);
    return *reinterpret_cast<unsigned short*>(&h);
}

// pack two floats to bf16x2 (RNE) -- v_cvt_pk_bf16_f32 on gfx950
__device__ inline unsigned int packbf2(float a, float b) {
    unsigned short ua = __builtin_bit_cast(unsigned short, (__bf16)a);
    unsigned short ub = __builtin_bit_cast(unsigned short, (__bf16)b);
    return (unsigned int)ua | ((unsigned int)ub << 16);
}

typedef const __attribute__((address_space(1))) unsigned int* gas_ptr;
typedef __attribute__((address_space(3))) unsigned int* las_ptr;
__device__ inline void gload16(const void* g, void* l) {
    __builtin_amdgcn_global_load_lds((gas_ptr)g, (las_ptr)l, 16, 0, 0);
}

// ---------------- fused prologue: cast x + transpose both weights (1 dispatch, was 3) -------
// region 0: blocks [0,8192)        cast x fp32 -> bf16 (4/thread)
// region 1: blocks [8192,11264)    W_qkv^T  (96 x 32 tile-blocks), Q cols pre-scaled by SCL
// region 2: blocks [11264,12288)   W_proj^T (32 x 32 tile-blocks)
__global__ __launch_bounds__(256) void prologue(const float* __restrict__ x,
                                                unsigned short* __restrict__ x_bf,
                                                const float* __restrict__ W_qkv,
                                                unsigned short* __restrict__ WqkvT,
                                                const float* __restrict__ W_proj,
                                                unsigned short* __restrict__ WprojT) {
    __shared__ float tile[32][33];
    const int blk = blockIdx.x;
    if (blk < 8192) {
        int i = blk * 256 + threadIdx.x;
        float4 v = ((const float4*)x)[i];
        ushort4 o;
        o.x = f2bf(v.x); o.y = f2bf(v.y); o.z = f2bf(v.z); o.w = f2bf(v.w);
        ((ushort4*)x_bf)[i] = o;
        return;
    }
    const float* in; unsigned short* outp; int C, srows, bx, byy; float scl;
    if (blk < 11264) {
        int t = blk - 8192;
        in = W_qkv; outp = WqkvT; C = 3 * DIM; srows = DIM; scl = SCL;
        bx = t % 96; byy = t / 96;
    } else {
        int t = blk - 11264;
        in = W_proj; outp = WprojT; C = DIM; srows = 0; scl = 1.f;
        bx = t & 31; byy = t >> 5;
    }
    const int R = DIM;
    int c0 = bx * 32, r0 = byy * 32;
    int tx = threadIdx.x & 31, ty = threadIdx.x >> 5; // 32 x 8
#pragma unroll
    for (int i = 0; i < 32; i += 8) {
        int r = r0 + ty + i, c = c0 + tx;
        tile[ty + i][tx] = in[(size_t)r * C + c];
    }
    __syncthreads();
#pragma unroll
    for (int i = 0; i < 32; i += 8) {
        int orow = c0 + ty + i, oc = r0 + tx;
        float v = tile[tx][ty + i];
        if (orow < srows) v *= scl;
        outp[(size_t)orow * R + oc] = f2bf(v);
    }
}

// ---------------- GEMM: C = A * Bt^T + bias, with fused K/V fragment-packing ----------------
// (unchanged from R5 -- verified). BK=64 as two 32-chunks; epilogue packs K/V quadrants
// straight into Kp/Vp fragment layouts via wave-private LDS overlay. XCD-chunk swizzle.
__global__ __launch_bounds__(256) void gemm_bt_bias(const unsigned short* __restrict__ A,
                                                    const unsigned short* __restrict__ Bt,
                                                    const float* __restrict__ bias,
                                                    unsigned short* __restrict__ Cq,
                                                    unsigned short* __restrict__ Kp,
                                                    unsigned short* __restrict__ Vp,
                                                    float* __restrict__ Cf,
                                                    int M, int N, int K, int qcols) {
    __shared__ unsigned short SMEM[18432];
    unsigned short* As0 = SMEM;            // As[kc] = SMEM + kc*4096
    unsigned short* Bs0 = SMEM + 8192;     // Bs[kc] = SMEM + 8192 + kc*4096
    const int tid = threadIdx.x;
    const int lane = tid & 63, wave = tid >> 6;
    const int wm = (wave >> 1) * 64, wn = (wave & 1) * 64;
    const int nwg = gridDim.x * gridDim.y;
    const int gflat = blockIdx.y * gridDim.x + blockIdx.x;
    const int bidx = (gflat & 7) * (nwg >> 3) + (gflat >> 3); // contiguous chunk per XCD
    const int bx = bidx % gridDim.x, byy = bidx / gridDim.x;
    const int rowA = byy * 128, rowB = bx * 128;
    const int fr = lane & 15, fo = (lane >> 4) * 8;

    f32x4 acc[4][4] = {};

    for (int k0 = 0; k0 < K; k0 += 64) {
#pragma unroll
        for (int kc = 0; kc < 2; kc++) {
#pragma unroll
            for (int c = 0; c < 2; c++) {
                int o = c * 4096 + tid * 16; // byte offset in 8KB chunk
                int r = o >> 6, cb = o & 63; // 64 B per row (32 bf16)
                int ldsb = c * 4096 + wave * 1024;
                gload16((const char*)A + ((size_t)(rowA + r) * K + k0 + kc * 32) * 2 + cb,
                        (char*)As0 + kc * 8192 + ldsb);
                gload16((const char*)Bt + ((size_t)(rowB + r) * K + k0 + kc * 32) * 2 + cb,
                        (char*)Bs0 + kc * 8192 + ldsb);
            }
        }
        __syncthreads();
#pragma unroll
        for (int kc = 0; kc < 2; kc++) {
            bf16x8 af[4], bfr[4];
#pragma unroll
            for (int i = 0; i < 4; i++) {
                af[i]  = *(const bf16x8*)(As0 + kc * 4096 + (wm + i * 16 + fr) * 32 + fo);
                bfr[i] = *(const bf16x8*)(Bs0 + kc * 4096 + (wn + i * 16 + fr) * 32 + fo);
            }
#pragma unroll
            for (int mi = 0; mi < 4; mi++)
#pragma unroll
                for (int ni = 0; ni < 4; ni++)
                    acc[mi][ni] = __builtin_amdgcn_mfma_f32_16x16x32_bf16(af[mi], bfr[ni],
                                                                          acc[mi][ni], 0, 0, 0);
        }
        __syncthreads();
    }

    // C/D layout (16x16): col = lane&15, row = (lane>>4)*4 + reg
    const int cn = lane & 15, cm = (lane >> 4) * 4;
    const int gn0 = rowB + wn; // wave's 64-col region: uniform Q/K/V classification

    if (Cf) {
        for (int ni = 0; ni < 4; ni++) {
            int gn = gn0 + ni * 16 + cn;
            float bv = bias[gn];
            if (gn < qcols) bv *= SCL;
            for (int mi = 0; mi < 4; mi++) {
#pragma unroll
                for (int r = 0; r < 4; r++) {
                    int gm = rowA + wm + mi * 16 + cm + r;
                    Cf[(size_t)gm * N + gn] = acc[mi][ni][r] + bv;
                }
            }
        }
    } else if (gn0 < 1024) {
        for (int ni = 0; ni < 4; ni++) {
            int gn = gn0 + ni * 16 + cn;
            float bv = bias[gn];
            if (gn < qcols) bv *= SCL;
            for (int mi = 0; mi < 4; mi++) {
#pragma unroll
                for (int r = 0; r < 4; r++) {
                    int gm = rowA + wm + mi * 16 + cm + r;
                    Cq[(size_t)gm * 1024 + gn] = f2bf(acc[mi][ni][r] + bv);
                }
            }
        }
    } else {
        // K or V: stage quadrant (bias added, bf16) into wave-private LDS tile [64][72]
        unsigned short* Lw = SMEM + wave * (64 * 72);
        for (int ni = 0; ni < 4; ni++) {
            float bv = bias[gn0 + ni * 16 + cn];
            for (int mi = 0; mi < 4; mi++) {
#pragma unroll
                for (int r = 0; r < 4; r++)
                    Lw[(mi * 16 + cm + r) * 72 + ni * 16 + cn] = f2bf(acc[mi][ni][r] + bv);
            }
        }
        __builtin_amdgcn_s_waitcnt(0); // drain lgkm: own ds_writes visible to own ds_reads
        const int b = rowA >> 11, s0g = rowA & 2047;
        const int mm = lane & 31, hh = lane >> 5;
        if (gn0 < 2048) {
            const int h = (gn0 - 1024) >> 6;
            const size_t by = (size_t)(b * 16 + h);
            const int kub = (s0g + wm) >> 5;
#pragma unroll
            for (int f = 0; f < 8; f++) {
                int ktl = f >> 2, ks = f & 3;
                uint4 d = *(const uint4*)&Lw[(ktl * 32 + mm) * 72 + ks * 16 + hh * 8];
                *(uint4*)(Kp + ((by * 64 + kub + ktl) * 4 + ks) * 512 + lane * 8) = d;
            }
        } else {
            const int h = (gn0 - 2048) >> 6;
            const size_t by = (size_t)(b * 16 + h);
            const int vub = (s0g + wm) >> 4;
#pragma unroll
            for (int f = 0; f < 8; f++) {
                int ksl = f >> 1, dt = f & 1;
                unsigned short tmp[8];
#pragma unroll
                for (int j = 0; j < 8; j++)
                    tmp[j] = Lw[(ksl * 16 + (j & 3) + 8 * (j >> 2) + 4 * hh) * 72 + dt * 32 + mm];
                *(uint4*)(Vp + ((by * 128 + vub + ksl) * 2 + dt) * 512 + lane * 8) =
                    *(uint4*)tmp;
            }
        }
    }
}

// ---- softmax + PV: exp2 of S^T C-frag, pack to bf16 (= PV A-frag), 4 accumulating MFMAs
__device__ inline void softmax_pv(const f32x16& cfrag, const bf16x8 vf[2][2],
                                  f32x16& o0, f32x16& o1, float& psum) {
    unsigned int pk[8];
    float es[8];
#pragma unroll
    for (int p = 0; p < 8; p++) {
        float e0 = __builtin_amdgcn_exp2f(cfrag[2 * p]);
        float e1 = __builtin_amdgcn_exp2f(cfrag[2 * p + 1]);
        es[p] = e0 + e1;
        pk[p] = packbf2(e0, e1);
    }
    psum += ((es[0] + es[1]) + (es[2] + es[3])) + ((es[4] + es[5]) + (es[6] + es[7]));
    u32x4 lo = {pk[0], pk[1], pk[2], pk[3]};
    u32x4 hi = {pk[4], pk[5], pk[6], pk[7]};
    bf16x8 pa0 = __builtin_bit_cast(bf16x8, lo); // keys [ku*32, +16) permuted
    bf16x8 pa1 = __builtin_bit_cast(bf16x8, hi); // keys [ku*32+16, +16)
    o0 = __builtin_amdgcn_mfma_f32_32x32x16_bf16(pa0, vf[0][0], o0, 0, 0, 0);
    o1 = __builtin_amdgcn_mfma_f32_32x32x16_bf16(pa0, vf[0][1], o1, 0, 0, 0);
    o0 = __builtin_amdgcn_mfma_f32_32x32x16_bf16(pa1, vf[1][0], o0, 0, 0, 0);
    o1 = __builtin_amdgcn_mfma_f32_32x32x16_bf16(pa1, vf[1][1], o1, 0, 0, 0);
}

// ---------------- flash attention v13: 32-q-per-wave tile -> 3-4 waves/SIMD ----------------
// R2/R4 proved the 64q tile needs ~190 regs (2 waves/SIMD, latency-bound; both pipes <50%).
// Halving the per-wave q-tile (qf 32->16, oacc 64->32, cfrag 32->16 regs) targets ~130 regs
// = 3-4 waves/SIMD: TLP replaces the lost qt-interleave ILP. Block = 64 q, 4 waves
// (qh, ksplit); grid 2048. K/V L2 traffic doubles to ~1GB (~17 TB/s < 34.5 roof; XCD
// clustering keeps 8 panels = 4MB = one L2). K double-buffer retained. Single-round combine.
// NO min-waves launch_bounds hint (R2/R4: caps below natural need -> catastrophic spill).
__global__ __launch_bounds__(256, 2) void attn_kernel(const unsigned short* __restrict__ Qb, // [8192][1024] prescaled
                                                      const unsigned short* __restrict__ Kp,
                                                      const unsigned short* __restrict__ Vp,
                                                      unsigned short* __restrict__ attnb) { // [8192][1024]
    __shared__ float Po[2][8 * 256]; // [qh] partial O from ksplit=1 wave (8 f32x4/lane)
    __shared__ float Pl[2][64];      // [qh] partial psum per lane
    const int tid = threadIdx.x;
    const int lane = tid & 63, wave = tid >> 6;
    const int qh = wave >> 1, ksplit = wave & 1;
    const int m31 = lane & 31, h = lane >> 5;
    // dispatch order: x fastest. gflat == dispatch index; round-robin over XCDs.
    const int gflat = blockIdx.y * gridDim.x + blockIdx.x; // [0, 2048)
    const int xcd = gflat & 7, slot = gflat >> 3;          // slot in [0, 256)
    const int by = xcd * 8 + (slot >> 5);                  // [0, 64): 8 panels/XCD
    const int qb = slot & 31;                              // [0, 32): 64-q blocks
    const int b = by >> 4;
    const int bS = b * SEQ, hcol = (by & 15) * HDIM;
    const int q0 = qb * 64 + qh * 32;

    // Q B-frags: qf[ks]: B[k=ks*16+h*8+j][n=q0+m31]
    bf16x8 qf[4];
#pragma unroll
    for (int ks = 0; ks < 4; ks++)
        qf[ks] = *(const bf16x8*)(Qb + (size_t)(bS + q0 + m31) * 1024 +
                                  hcol + ks * 16 + h * 8);

    f32x16 oacc[2] = {}; // [dt]: C row=q, col=d=dt*32+m31
    float psum = 0.f;

    const unsigned short* kbase = Kp + (size_t)by * 64 * 2048 + lane * 8;
    const unsigned short* vbase = Vp + (size_t)by * 128 * 1024 + lane * 8;

    const int ku0 = ksplit * 32; // each wave: 32 key-units of 32 keys
    bf16x8 kfa[4], kfb[4];
    {
        const unsigned short* kp = kbase + (size_t)ku0 * 2048;
#pragma unroll
        for (int ks = 0; ks < 4; ks++) kfa[ks] = *(const bf16x8*)(kp + ks * 512);
    }
    for (int ki = 0; ki < 32; ki += 2) {
        // even step: compute with kfa, prefetch K(ki+1) -> kfb
        {
            int ku = ku0 + ki;
            bf16x8 vf[2][2];
#pragma unroll
            for (int ks = 0; ks < 2; ks++) {
                const unsigned short* vp = vbase + ((size_t)ku * 2 + ks) * 1024;
                vf[ks][0] = *(const bf16x8*)(vp);
                vf[ks][1] = *(const bf16x8*)(vp + 512);
            }
            const unsigned short* kpn = kbase + (size_t)(ku + 1) * 2048;
#pragma unroll
            for (int ks = 0; ks < 4; ks++) kfb[ks] = *(const bf16x8*)(kpn + ks * 512);
            f32x16 cf = {};
#pragma unroll
            for (int ks = 0; ks < 4; ks++)
                cf = __builtin_amdgcn_mfma_f32_32x32x16_bf16(kfa[ks], qf[ks], cf, 0, 0, 0);
            softmax_pv(cf, vf, oacc[0], oacc[1], psum);
        }
        // odd step: compute with kfb, prefetch K(ki+2) -> kfa (clamped, branchless)
        {
            int ku = ku0 + ki + 1;
            bf16x8 vf[2][2];
#pragma unroll
            for (int ks = 0; ks < 2; ks++) {
                const unsigned short* vp = vbase + ((size_t)ku * 2 + ks) * 1024;
                vf[ks][0] = *(const bf16x8*)(vp);
                vf[ks][1] = *(const bf16x8*)(vp + 512);
            }
            int kup = ku0 + ((ki + 2 < 32) ? (ki + 2) : 31); // last iter: redundant reload
            const unsigned short* kpn = kbase + (size_t)kup * 2048;
#pragma unroll
            for (int ks = 0; ks < 4; ks++) kfa[ks] = *(const bf16x8*)(kpn + ks * 512);
            f32x16 cf = {};
#pragma unroll
            for (int ks = 0; ks < 4; ks++)
                cf = __builtin_amdgcn_mfma_f32_32x32x16_bf16(kfb[ks], qf[ks], cf, 0, 0, 0);
            softmax_pv(cf, vf, oacc[0], oacc[1], psum);
        }
    }

    // single-round combine: ksplit=1 parks partial (O, l), ksplit=0 sums + writes.
    if (ksplit == 1) {
#pragma unroll
        for (int dt = 0; dt < 2; dt++)
#pragma unroll
            for (int c = 0; c < 4; c++) {
                f32x4 v = {oacc[dt][c * 4 + 0], oacc[dt][c * 4 + 1],
                           oacc[dt][c * 4 + 2], oacc[dt][c * 4 + 3]};
                *(f32x4*)&Po[qh][(dt * 4 + c) * 256 + lane * 4] = v;
            }
        Pl[qh][lane] = psum;
    }
    __syncthreads();
    if (ksplit == 0) {
#pragma unroll
        for (int dt = 0; dt < 2; dt++)
#pragma unroll
            for (int c = 0; c < 4; c++) {
                f32x4 v = *(const f32x4*)&Po[qh][(dt * 4 + c) * 256 + lane * 4];
#pragma unroll
                for (int j = 0; j < 4; j++) oacc[dt][c * 4 + j] += v[j];
            }
        psum += Pl[qh][lane];

        // epilogue: l[q] = psum(h=0)+psum(h=1); C rows: row=(r&3)+8*(r>>2)+4h
        float lt = psum + __shfl_xor(psum, 32, 64);
        float rl = 1.f / lt; // valid on lanes where m31 == q
#pragma unroll
        for (int r = 0; r < 16; r++) {
            int row = (r & 3) + 8 * (r >> 2) + 4 * h;
            float rlr = __shfl(rl, row, 64);
            size_t orow = (size_t)(bS + q0 + row) * 1024 + hcol;
            attnb[orow + m31]      = f2bf(oacc[0][r] * rlr);
            attnb[orow + 32 + m31] = f2bf(oacc[1][r] * rlr);
        }
    }
}

extern "C" void kernel_launch(void* const* d_in, const int* in_sizes, int n_in,
                              void* d_out, int out_size, void* d_ws, size_t ws_size,
                              hipStream_t stream) {
    const float* x      = (const float*)d_in[0]; // [4,2048,1024]
    const float* W_qkv  = (const float*)d_in[1]; // [1024,3072]
    const float* b_qkv  = (const float*)d_in[2]; // [3072]
    const float* W_proj = (const float*)d_in[3]; // [1024,1024]
    const float* b_proj = (const float*)d_in[4]; // [1024]
    float* out = (float*)d_out;                  // [4,2048,1024]

    char* ws = (char*)d_ws;
    // lifetimes: x_bf,WqkvT die after gemm1 (Kp/Vp written DURING gemm1 -> own regions);
    // attnb aliases x_bf. Peak 75.5 MiB.
    unsigned short* x_bf   = (unsigned short*)(ws);                // [0, 16.8M)
    unsigned short* WqkvT  = (unsigned short*)(ws + 16777216);     // [16.8M, 23.1M)
    unsigned short* Qb     = (unsigned short*)(ws + 23068672);     // [23.1M, 39.8M)
    unsigned short* Kp     = (unsigned short*)(ws + 39845888);     // [39.8M, 56.6M)
    unsigned short* Vp     = (unsigned short*)(ws + 56623104);     // [56.6M, 73.4M)
    unsigned short* WprojT = (unsigned short*)(ws + 73400320);     // [73.4M, 75.5M)
    unsigned short* attnb  = (unsigned short*)(ws);                // reuses x_bf

    // 1) fused prologue: cast x + transpose W_qkv (Q cols pre-scaled) + transpose W_proj
    prologue<<<12288, 256, 0, stream>>>(x, x_bf, W_qkv, WqkvT, W_proj, WprojT);

    // 2) qkv = x @ W_qkv + b_qkv -> Qb (bf16, scaled) + Kp/Vp (fragment-packed, fused)
    gemm_bt_bias<<<dim3(3 * DIM / 128, ROWS / 128), 256, 0, stream>>>(
        x_bf, WqkvT, b_qkv, Qb, Kp, Vp, nullptr, ROWS, 3 * DIM, DIM, DIM);

    // 3) attention (x_bf dead; attnb reuses it): 64 q/block, KV split across wave pairs
    attn_kernel<<<dim3(SEQ / 64, BATCH * NHEADS), 256, 0, stream>>>(Qb, Kp, Vp, attnb);

    // 4) out = attn @ W_proj + b_proj (fp32 out)
    gemm_bt_bias<<<dim3(DIM / 128, ROWS / 128), 256, 0, stream>>>(
        attnb, WprojT, b_proj, nullptr, nullptr, nullptr, out, ROWS, DIM, DIM, 0);
}

// Round 8
// 261.796 us; speedup vs baseline: 1.2595x; 1.2595x over previous
//
#include <hip/hip_runtime.h>
#include <hip/hip_bf16.h>

typedef __attribute__((ext_vector_type(8))) __bf16 bf16x8;
typedef __attribute__((ext_vector_type(4))) float f32x4;
typedef __attribute__((ext_vector_type(16))) float f32x16;
typedef __attribute__((ext_vector_type(4))) unsigned int u32x4;

#define DIM 1024
#define NHEADS 16
#define HDIM 64
#define BATCH 4
#define SEQ 2048
#define ROWS (BATCH * SEQ) /* 8192 */
#define SCL 0.18033688011112042f /* 0.125 * log2(e) */

__device__ inline unsigned short f2bf(float f) {
    __hip_bfloat16 h = __float2bfloat16(f);
    return *reinterpret_cast<unsigned short*>(&h);
}

// pack two floats to bf16x2 (RNE) -- v_cvt_pk_bf16_f32 on gfx950
__device__ inline unsigned int packbf2(float a, float b) {
    unsigned short ua = __builtin_bit_cast(unsigned short, (__bf16)a);
    unsigned short ub = __builtin_bit_cast(unsigned short, (__bf16)b);
    return (unsigned int)ua | ((unsigned int)ub << 16);
}

typedef const __attribute__((address_space(1))) unsigned int* gas_ptr;
typedef __attribute__((address_space(3))) unsigned int* las_ptr;
__device__ inline void gload16(const void* g, void* l) {
    __builtin_amdgcn_global_load_lds((gas_ptr)g, (las_ptr)l, 16, 0, 0);
}

// ---------------- fused prologue: cast x + transpose both weights (1 dispatch, was 3) -------
// region 0: blocks [0,8192)        cast x fp32 -> bf16 (4/thread)
// region 1: blocks [8192,11264)    W_qkv^T  (96 x 32 tile-blocks), Q cols pre-scaled by SCL
// region 2: blocks [11264,12288)   W_proj^T (32 x 32 tile-blocks)
__global__ __launch_bounds__(256) void prologue(const float* __restrict__ x,
                                                unsigned short* __restrict__ x_bf,
                                                const float* __restrict__ W_qkv,
                                                unsigned short* __restrict__ WqkvT,
                                                const float* __restrict__ W_proj,
                                                unsigned short* __restrict__ WprojT) {
    __shared__ float tile[32][33];
    const int blk = blockIdx.x;
    if (blk < 8192) {
        int i = blk * 256 + threadIdx.x;
        float4 v = ((const float4*)x)[i];
        ushort4 o;
        o.x = f2bf(v.x); o.y = f2bf(v.y); o.z = f2bf(v.z); o.w = f2bf(v.w);
        ((ushort4*)x_bf)[i] = o;
        return;
    }
    const float* in; unsigned short* outp; int C, srows, bx, byy; float scl;
    if (blk < 11264) {
        int t = blk - 8192;
        in = W_qkv; outp = WqkvT; C = 3 * DIM; srows = DIM; scl = SCL;
        bx = t % 96; byy = t / 96;
    } else {
        int t = blk - 11264;
        in = W_proj; outp = WprojT; C = DIM; srows = 0; scl = 1.f;
        bx = t & 31; byy = t >> 5;
    }
    const int R = DIM;
    int c0 = bx * 32, r0 = byy * 32;
    int tx = threadIdx.x & 31, ty = threadIdx.x >> 5; // 32 x 8
#pragma unroll
    for (int i = 0; i < 32; i += 8) {
        int r = r0 + ty + i, c = c0 + tx;
        tile[ty + i][tx] = in[(size_t)r * C + c];
    }
    __syncthreads();
#pragma unroll
    for (int i = 0; i < 32; i += 8) {
        int orow = c0 + ty + i, oc = r0 + tx;
        float v = tile[tx][ty + i];
        if (orow < srows) v *= scl;
        outp[(size_t)orow * R + oc] = f2bf(v);
    }
}

// ---------------- GEMM: C = A * Bt^T + bias, with fused K/V fragment-packing ----------------
// (R5-verified). BK=64 as two 32-chunks; epilogue packs K/V quadrants straight into
// Kp/Vp fragment layouts via wave-private LDS overlay. XCD-chunk swizzle.
__global__ __launch_bounds__(256) void gemm_bt_bias(const unsigned short* __restrict__ A,
                                                    const unsigned short* __restrict__ Bt,
                                                    const float* __restrict__ bias,
                                                    unsigned short* __restrict__ Cq,
                                                    unsigned short* __restrict__ Kp,
                                                    unsigned short* __restrict__ Vp,
                                                    float* __restrict__ Cf,
                                                    int M, int N, int K, int qcols) {
    __shared__ unsigned short SMEM[18432];
    unsigned short* As0 = SMEM;            // As[kc] = SMEM + kc*4096
    unsigned short* Bs0 = SMEM + 8192;     // Bs[kc] = SMEM + 8192 + kc*4096
    const int tid = threadIdx.x;
    const int lane = tid & 63, wave = tid >> 6;
    const int wm = (wave >> 1) * 64, wn = (wave & 1) * 64;
    const int nwg = gridDim.x * gridDim.y;
    const int gflat = blockIdx.y * gridDim.x + blockIdx.x;
    const int bidx = (gflat & 7) * (nwg >> 3) + (gflat >> 3); // contiguous chunk per XCD
    const int bx = bidx % gridDim.x, byy = bidx / gridDim.x;
    const int rowA = byy * 128, rowB = bx * 128;
    const int fr = lane & 15, fo = (lane >> 4) * 8;

    f32x4 acc[4][4] = {};

    for (int k0 = 0; k0 < K; k0 += 64) {
#pragma unroll
        for (int kc = 0; kc < 2; kc++) {
#pragma unroll
            for (int c = 0; c < 2; c++) {
                int o = c * 4096 + tid * 16; // byte offset in 8KB chunk
                int r = o >> 6, cb = o & 63; // 64 B per row (32 bf16)
                int ldsb = c * 4096 + wave * 1024;
                gload16((const char*)A + ((size_t)(rowA + r) * K + k0 + kc * 32) * 2 + cb,
                        (char*)As0 + kc * 8192 + ldsb);
                gload16((const char*)Bt + ((size_t)(rowB + r) * K + k0 + kc * 32) * 2 + cb,
                        (char*)Bs0 + kc * 8192 + ldsb);
            }
        }
        __syncthreads();
#pragma unroll
        for (int kc = 0; kc < 2; kc++) {
            bf16x8 af[4], bfr[4];
#pragma unroll
            for (int i = 0; i < 4; i++) {
                af[i]  = *(const bf16x8*)(As0 + kc * 4096 + (wm + i * 16 + fr) * 32 + fo);
                bfr[i] = *(const bf16x8*)(Bs0 + kc * 4096 + (wn + i * 16 + fr) * 32 + fo);
            }
#pragma unroll
            for (int mi = 0; mi < 4; mi++)
#pragma unroll
                for (int ni = 0; ni < 4; ni++)
                    acc[mi][ni] = __builtin_amdgcn_mfma_f32_16x16x32_bf16(af[mi], bfr[ni],
                                                                          acc[mi][ni], 0, 0, 0);
        }
        __syncthreads();
    }

    // C/D layout (16x16): col = lane&15, row = (lane>>4)*4 + reg
    const int cn = lane & 15, cm = (lane >> 4) * 4;
    const int gn0 = rowB + wn; // wave's 64-col region: uniform Q/K/V classification

    if (Cf) {
        for (int ni = 0; ni < 4; ni++) {
            int gn = gn0 + ni * 16 + cn;
            float bv = bias[gn];
            if (gn < qcols) bv *= SCL;
            for (int mi = 0; mi < 4; mi++) {
#pragma unroll
                for (int r = 0; r < 4; r++) {
                    int gm = rowA + wm + mi * 16 + cm + r;
                    Cf[(size_t)gm * N + gn] = acc[mi][ni][r] + bv;
                }
            }
        }
    } else if (gn0 < 1024) {
        for (int ni = 0; ni < 4; ni++) {
            int gn = gn0 + ni * 16 + cn;
            float bv = bias[gn];
            if (gn < qcols) bv *= SCL;
            for (int mi = 0; mi < 4; mi++) {
#pragma unroll
                for (int r = 0; r < 4; r++) {
                    int gm = rowA + wm + mi * 16 + cm + r;
                    Cq[(size_t)gm * 1024 + gn] = f2bf(acc[mi][ni][r] + bv);
                }
            }
        }
    } else {
        // K or V: stage quadrant (bias added, bf16) into wave-private LDS tile [64][72]
        unsigned short* Lw = SMEM + wave * (64 * 72);
        for (int ni = 0; ni < 4; ni++) {
            float bv = bias[gn0 + ni * 16 + cn];
            for (int mi = 0; mi < 4; mi++) {
#pragma unroll
                for (int r = 0; r < 4; r++)
                    Lw[(mi * 16 + cm + r) * 72 + ni * 16 + cn] = f2bf(acc[mi][ni][r] + bv);
            }
        }
        __builtin_amdgcn_s_waitcnt(0); // drain lgkm: own ds_writes visible to own ds_reads
        const int b = rowA >> 11, s0g = rowA & 2047;
        const int mm = lane & 31, hh = lane >> 5;
        if (gn0 < 2048) {
            const int h = (gn0 - 1024) >> 6;
            const size_t by = (size_t)(b * 16 + h);
            const int kub = (s0g + wm) >> 5;
#pragma unroll
            for (int f = 0; f < 8; f++) {
                int ktl = f >> 2, ks = f & 3;
                uint4 d = *(const uint4*)&Lw[(ktl * 32 + mm) * 72 + ks * 16 + hh * 8];
                *(uint4*)(Kp + ((by * 64 + kub + ktl) * 4 + ks) * 512 + lane * 8) = d;
            }
        } else {
            const int h = (gn0 - 2048) >> 6;
            const size_t by = (size_t)(b * 16 + h);
            const int vub = (s0g + wm) >> 4;
#pragma unroll
            for (int f = 0; f < 8; f++) {
                int ksl = f >> 1, dt = f & 1;
                unsigned short tmp[8];
#pragma unroll
                for (int j = 0; j < 8; j++)
                    tmp[j] = Lw[(ksl * 16 + (j & 3) + 8 * (j >> 2) + 4 * hh) * 72 + dt * 32 + mm];
                *(uint4*)(Vp + ((by * 128 + vub + ksl) * 2 + dt) * 512 + lane * 8) =
                    *(uint4*)tmp;
            }
        }
    }
}

// ---- softmax + PV for one q-tile: exp2 of S^T C-frag, pack to bf16 (= PV A-frag), 2 MFMAs/dt
__device__ inline void softmax_pv(const f32x16& cfrag, const bf16x8 vf[2][2],
                                  f32x16& o0, f32x16& o1, float& psum) {
    unsigned int pk[8];
    float es[8];
#pragma unroll
    for (int p = 0; p < 8; p++) {
        float e0 = __builtin_amdgcn_exp2f(cfrag[2 * p]);
        float e1 = __builtin_amdgcn_exp2f(cfrag[2 * p + 1]);
        es[p] = e0 + e1;
        pk[p] = packbf2(e0, e1);
    }
    psum += ((es[0] + es[1]) + (es[2] + es[3])) + ((es[4] + es[5]) + (es[6] + es[7]));
    u32x4 lo = {pk[0], pk[1], pk[2], pk[3]};
    u32x4 hi = {pk[4], pk[5], pk[6], pk[7]};
    bf16x8 pa0 = __builtin_bit_cast(bf16x8, lo); // keys [ku*32, +16) permuted
    bf16x8 pa1 = __builtin_bit_cast(bf16x8, hi); // keys [ku*32+16, +16)
    o0 = __builtin_amdgcn_mfma_f32_32x32x16_bf16(pa0, vf[0][0], o0, 0, 0, 0);
    o1 = __builtin_amdgcn_mfma_f32_32x32x16_bf16(pa0, vf[0][1], o1, 0, 0, 0);
    o0 = __builtin_amdgcn_mfma_f32_32x32x16_bf16(pa1, vf[1][0], o0, 0, 0, 0);
    o1 = __builtin_amdgcn_mfma_f32_32x32x16_bf16(pa1, vf[1][1], o1, 0, 0, 0);
}

// ---- one 32-key step, qt-interleaved: QK0,QK1 issue back-to-back (two independent
// 4-MFMA chains hide each other); then sm0, PV0 (MFMAs in flight), sm1 (VALU overlaps
// PV0), PV1. MFMA issue is non-blocking within a wave -> compile-time MFMA||VALU overlap.
__device__ inline void attn_step(const bf16x8 kf[4], const bf16x8 vf[2][2],
                                 const bf16x8 qf[2][4], f32x16 oacc[2][2], float psum[2]) {
    f32x16 cf0 = {}, cf1 = {};
#pragma unroll
    for (int ks = 0; ks < 4; ks++)
        cf0 = __builtin_amdgcn_mfma_f32_32x32x16_bf16(kf[ks], qf[0][ks], cf0, 0, 0, 0);
#pragma unroll
    for (int ks = 0; ks < 4; ks++)
        cf1 = __builtin_amdgcn_mfma_f32_32x32x16_bf16(kf[ks], qf[1][ks], cf1, 0, 0, 0);
    softmax_pv(cf0, vf, oacc[0][0], oacc[0][1], psum[0]);
    softmax_pv(cf1, vf, oacc[1][0], oacc[1][1], psum[1]);
}

// ---------------- flash attention v11 (R3/R5-proven): 64q/wave, K-dbuf + qt-interleave -----
// OPERATING-POINT NOTE (triple-confirmed): this kernel runs at 2 waves/SIMD, ~190 regs.
//   R2: cap 128 -> acc spill, 1.5 GB scratch, 619 µs.  R4: cap 170 -> 60 MB scratch, 123 µs.
//   R7: 32q tile (more waves, less regs) -> arithmetic intensity halved, 150 µs.
// 64q x 64d per wave at 2 waves/SIMD with qt-interleave ILP = ~82 µs, MFMA+VALU ~84%
// combined. Do NOT shrink the tile; do NOT add a min-waves launch_bounds hint.
__global__ __launch_bounds__(256, 2) void attn_kernel(const unsigned short* __restrict__ Qb, // [8192][1024] prescaled
                                                      const unsigned short* __restrict__ Kp,
                                                      const unsigned short* __restrict__ Vp,
                                                      unsigned short* __restrict__ attnb) { // [8192][1024]
    __shared__ float Po[2][8 * 256]; // [qpair] partial O (one qt round at a time)
    __shared__ float Pl[2][128];     // [qpair] partial psum[2] per lane
    const int tid = threadIdx.x;
    const int lane = tid & 63, wave = tid >> 6;
    const int qpair = wave >> 1, ksplit = wave & 1;
    const int m31 = lane & 31, h = lane >> 5;
    // dispatch order: x fastest. gflat == dispatch index; round-robin over XCDs.
    const int gflat = blockIdx.y * gridDim.x + blockIdx.x; // [0, 1024)
    const int xcd = gflat & 7, slot = gflat >> 3;          // slot in [0, 128)
    const int by = xcd * 8 + (slot >> 4);                  // [0, 64): 8 panels/XCD
    const int qb = slot & 15;                              // [0, 16)
    const int b = by >> 4;
    const int bS = b * SEQ, hcol = (by & 15) * HDIM;
    const int q0 = qb * 128 + qpair * 64;

    // Q B-frags: qf[qt][ks]: B[k=ks*16+h*8+j][n=q0+qt*32+m31]
    bf16x8 qf[2][4];
#pragma unroll
    for (int qt = 0; qt < 2; qt++)
#pragma unroll
        for (int ks = 0; ks < 4; ks++)
            qf[qt][ks] = *(const bf16x8*)(Qb + (size_t)(bS + q0 + qt * 32 + m31) * 1024 +
                                          hcol + ks * 16 + h * 8);

    f32x16 oacc[2][2] = {}; // [qt][dt]: C row=q, col=d=dt*32+m31
    float psum[2] = {0.f, 0.f};

    const unsigned short* kbase = Kp + (size_t)by * 64 * 2048 + lane * 8;
    const unsigned short* vbase = Vp + (size_t)by * 128 * 1024 + lane * 8;

    const int ku0 = ksplit * 32; // each wave: 32 key-units of 32 keys
    bf16x8 kfa[4], kfb[4];
    {
        const unsigned short* kp = kbase + (size_t)ku0 * 2048;
#pragma unroll
        for (int ks = 0; ks < 4; ks++) kfa[ks] = *(const bf16x8*)(kp + ks * 512);
    }
    for (int ki = 0; ki < 32; ki += 2) {
        // even step: compute with kfa, prefetch K(ki+1) -> kfb
        {
            int ku = ku0 + ki;
            bf16x8 vf[2][2];
#pragma unroll
            for (int ks = 0; ks < 2; ks++) {
                const unsigned short* vp = vbase + ((size_t)ku * 2 + ks) * 1024;
                vf[ks][0] = *(const bf16x8*)(vp);
                vf[ks][1] = *(const bf16x8*)(vp + 512);
            }
            const unsigned short* kpn = kbase + (size_t)(ku + 1) * 2048;
#pragma unroll
            for (int ks = 0; ks < 4; ks++) kfb[ks] = *(const bf16x8*)(kpn + ks * 512);
            attn_step(kfa, vf, qf, oacc, psum);
        }
        // odd step: compute with kfb, prefetch K(ki+2) -> kfa (clamped, branchless)
        {
            int ku = ku0 + ki + 1;
            bf16x8 vf[2][2];
#pragma unroll
            for (int ks = 0; ks < 2; ks++) {
                const unsigned short* vp = vbase + ((size_t)ku * 2 + ks) * 1024;
                vf[ks][0] = *(const bf16x8*)(vp);
                vf[ks][1] = *(const bf16x8*)(vp + 512);
            }
            int kup = ku0 + ((ki + 2 < 32) ? (ki + 2) : 31); // last iter: redundant reload
            const unsigned short* kpn = kbase + (size_t)kup * 2048;
#pragma unroll
            for (int ks = 0; ks < 4; ks++) kfa[ks] = *(const bf16x8*)(kpn + ks * 512);
            attn_step(kfb, vf, qf, oacc, psum);
        }
    }

    // two-round combine (qt=0 then qt=1): ksplit=1 parks partials, ksplit=0 sums.
#pragma unroll
    for (int qt = 0; qt < 2; qt++) {
        if (ksplit == 1) {
#pragma unroll
            for (int dt = 0; dt < 2; dt++)
#pragma unroll
                for (int c = 0; c < 4; c++) {
                    f32x4 v = {oacc[qt][dt][c * 4 + 0], oacc[qt][dt][c * 4 + 1],
                               oacc[qt][dt][c * 4 + 2], oacc[qt][dt][c * 4 + 3]};
                    *(f32x4*)&Po[qpair][(dt * 4 + c) * 256 + lane * 4] = v;
                }
            if (qt == 0)
                *(float2*)&Pl[qpair][lane * 2] = make_float2(psum[0], psum[1]);
        }
        __syncthreads();
        if (ksplit == 0) {
#pragma unroll
            for (int dt = 0; dt < 2; dt++)
#pragma unroll
                for (int c = 0; c < 4; c++) {
                    f32x4 v = *(const f32x4*)&Po[qpair][(dt * 4 + c) * 256 + lane * 4];
#pragma unroll
                    for (int j = 0; j < 4; j++) oacc[qt][dt][c * 4 + j] += v[j];
                }
            if (qt == 0) {
                float2 pl = *(const float2*)&Pl[qpair][lane * 2];
                psum[0] += pl.x; psum[1] += pl.y;
            }
        }
        if (qt == 0) __syncthreads(); // Po reused by round 2
    }

    if (ksplit == 0) {
        // epilogue: l[q] = psum(h=0)+psum(h=1); C rows: row=(r&3)+8*(r>>2)+4h
#pragma unroll
        for (int qt = 0; qt < 2; qt++) {
            float lt = psum[qt] + __shfl_xor(psum[qt], 32, 64);
            float rl = 1.f / lt; // valid on lanes where m31 == q
#pragma unroll
            for (int r = 0; r < 16; r++) {
                int row = (r & 3) + 8 * (r >> 2) + 4 * h;
                float rlr = __shfl(rl, row, 64);
                size_t orow = (size_t)(bS + q0 + qt * 32 + row) * 1024 + hcol;
                attnb[orow + m31]      = f2bf(oacc[qt][0][r] * rlr);
                attnb[orow + 32 + m31] = f2bf(oacc[qt][1][r] * rlr);
            }
        }
    }
}

extern "C" void kernel_launch(void* const* d_in, const int* in_sizes, int n_in,
                              void* d_out, int out_size, void* d_ws, size_t ws_size,
                              hipStream_t stream) {
    const float* x      = (const float*)d_in[0]; // [4,2048,1024]
    const float* W_qkv  = (const float*)d_in[1]; // [1024,3072]
    const float* b_qkv  = (const float*)d_in[2]; // [3072]
    const float* W_proj = (const float*)d_in[3]; // [1024,1024]
    const float* b_proj = (const float*)d_in[4]; // [1024]
    float* out = (float*)d_out;                  // [4,2048,1024]

    char* ws = (char*)d_ws;
    // lifetimes: x_bf,WqkvT die after gemm1 (Kp/Vp written DURING gemm1 -> own regions);
    // attnb aliases x_bf. Peak 75.5 MiB.
    unsigned short* x_bf   = (unsigned short*)(ws);                // [0, 16.8M)
    unsigned short* WqkvT  = (unsigned short*)(ws + 16777216);     // [16.8M, 23.1M)
    unsigned short* Qb     = (unsigned short*)(ws + 23068672);     // [23.1M, 39.8M)
    unsigned short* Kp     = (unsigned short*)(ws + 39845888);     // [39.8M, 56.6M)
    unsigned short* Vp     = (unsigned short*)(ws + 56623104);     // [56.6M, 73.4M)
    unsigned short* WprojT = (unsigned short*)(ws + 73400320);     // [73.4M, 75.5M)
    unsigned short* attnb  = (unsigned short*)(ws);                // reuses x_bf

    // 1) fused prologue: cast x + transpose W_qkv (Q cols pre-scaled) + transpose W_proj
    prologue<<<12288, 256, 0, stream>>>(x, x_bf, W_qkv, WqkvT, W_proj, WprojT);

    // 2) qkv = x @ W_qkv + b_qkv -> Qb (bf16, scaled) + Kp/Vp (fragment-packed, fused)
    gemm_bt_bias<<<dim3(3 * DIM / 128, ROWS / 128), 256, 0, stream>>>(
        x_bf, WqkvT, b_qkv, Qb, Kp, Vp, nullptr, ROWS, 3 * DIM, DIM, DIM);

    // 3) attention (x_bf dead; attnb reuses it): 128 q/block, KV split across wave pairs
    attn_kernel<<<dim3(SEQ / 128, BATCH * NHEADS), 256, 0, stream>>>(Qb, Kp, Vp, attnb);

    // 4) out = attn @ W_proj + b_proj (fp32 out)
    gemm_bt_bias<<<dim3(DIM / 128, ROWS / 128), 256, 0, stream>>>(
        attnb, WprojT, b_proj, nullptr, nullptr, nullptr, out, ROWS, DIM, DIM, 0);
}